// Round 9
// baseline (174.702 us; speedup 1.0000x reference)
//
#include <hip/hip_runtime.h>
#include <hip/hip_bf16.h>

typedef __attribute__((ext_vector_type(8))) short bf16x8;
typedef __attribute__((ext_vector_type(4))) float f32x4;
typedef __attribute__((ext_vector_type(16))) float f32x16;
typedef unsigned short u16;
typedef unsigned int u32;

__device__ __forceinline__ u16 f2bf(float f) {  // RNE
  union { float f; unsigned int u; } v; v.f = f;
  return (u16)((v.u + 0x7fffu + ((v.u >> 16) & 1u)) >> 16);
}
__device__ __forceinline__ u32 pack_rne(float a, float b) {  // two bf16 RNE in one u32
  return (u32)f2bf(a) | ((u32)f2bf(b) << 16);
}
// pack two floats -> two bf16 in one u32 (round-half-up; P matrix only); f0 in low half
__device__ __forceinline__ u32 pack_bf2(float f0, float f1) {
  union { float f; unsigned int u; } a, b; a.f = f0; b.f = f1;
  return __builtin_amdgcn_perm(b.u + 0x8000u, a.u + 0x8000u, 0x07060302u);
}

#define GLOAD_LDS16(g, l) __builtin_amdgcn_global_load_lds( \
    (const __attribute__((address_space(1))) void*)(g),     \
    (__attribute__((address_space(3))) void*)(l), 16, 0, 0)

// ---------------- fp32 -> bf16 conversion, all tensors in one launch ----------------
__global__ __launch_bounds__(256) void conv_all(const float* __restrict__ x,
                                                const float* __restrict__ wq, const float* __restrict__ wk,
                                                const float* __restrict__ wv, const float* __restrict__ wo,
                                                u16* __restrict__ xb, u16* __restrict__ qo, u16* __restrict__ ko,
                                                u16* __restrict__ vo, u16* __restrict__ oo) {
  int y = blockIdx.y;
  const float* src; u16* dst;
  if (y < 4) { src = x + (size_t)y * 1048576; dst = xb + (size_t)y * 1048576; }
  else if (y == 4) { src = wq; dst = qo; }
  else if (y == 5) { src = wk; dst = ko; }
  else if (y == 6) { src = wv; dst = vo; }
  else { src = wo; dst = oo; }
  int i = (blockIdx.x * 256 + threadIdx.x) * 4;
  float4 v = *(const float4*)(src + i);
  ushort4 o;
  o.x = f2bf(v.x); o.y = f2bf(v.y); o.z = f2bf(v.z); o.w = f2bf(v.w);
  *(ushort4*)(dst + i) = o;
}

// ---------------- shared GEMM mainloop (128M x 128N): acc = A[M,K] @ W[N,K]^T ----------------
template <bool SW>
__device__ __forceinline__ void gemm_main(const u16* __restrict__ A, const u16* __restrict__ W,
                                          u16* As, u16* Bs, int m0, int n0, int K,
                                          f32x4 acc[4][4]) {
  int tid = threadIdx.x, wave = tid >> 6, lane = tid & 63;
  int lane15 = lane & 15, quad = lane >> 4;
  int wm = (wave >> 1) * 64, wn = (wave & 1) * 64;
  for (int k0 = 0; k0 < K; k0 += 64) {
    __syncthreads();
#pragma unroll
    for (int i = 0; i < 4; i++) {
      int rbase = wave * 32 + i * 8;
      int rloc = rbase + (lane >> 3);
      int ca = ((lane & 7) ^ (rloc & 7)) * 8;
      GLOAD_LDS16(A + (size_t)(m0 + rloc) * K + k0 + ca, As + rbase * 64);
      GLOAD_LDS16(W + (size_t)(n0 + rloc) * K + k0 + ca, Bs + rbase * 64);
    }
    __syncthreads();
#pragma unroll
    for (int kc = 0; kc < 2; kc++) {
      bf16x8 a[4], b[4];
#pragma unroll
      for (int mi = 0; mi < 4; mi++) {
        int m = wm + mi * 16 + lane15;
        a[mi] = *(const bf16x8*)(As + m * 64 + (((kc * 4 + quad) ^ (m & 7)) * 8));
      }
#pragma unroll
      for (int ni = 0; ni < 4; ni++) {
        int n = wn + ni * 16 + lane15;
        b[ni] = *(const bf16x8*)(Bs + n * 64 + (((kc * 4 + quad) ^ (n & 7)) * 8));
      }
#pragma unroll
      for (int mi = 0; mi < 4; mi++)
#pragma unroll
        for (int ni = 0; ni < 4; ni++)
          acc[mi][ni] = SW ? __builtin_amdgcn_mfma_f32_16x16x32_bf16(b[ni], a[mi], acc[mi][ni], 0, 0, 0)
                           : __builtin_amdgcn_mfma_f32_16x16x32_bf16(a[mi], b[ni], acc[mi][ni], 0, 0, 0);
    }
  }
}

// QKV fused: z=0 -> Q (pre-scaled), z=1 -> K, z=2 -> V^T [b,h,dh,n].
// Epilogue: acc -> swizzled LDS -> coalesced 16B stores (wave covers contiguous 8KB).
__global__ __launch_bounds__(256, 3) void gemm_qkv(const u16* __restrict__ xb,
                                                   const u16* __restrict__ wq, const u16* __restrict__ wk,
                                                   const u16* __restrict__ wv,
                                                   u16* __restrict__ Qb, u16* __restrict__ Kb,
                                                   u16* __restrict__ Vtg) {
  __shared__ __align__(16) u16 SH[16384];  // mainloop: As|Bs ; epilogue: 128x128 u16 transpose buf
  u16* As = SH;
  u16* Bs = SH + 8192;
  const int K = 1024;
  int z = blockIdx.z;
  const u16* W = (z == 0) ? wq : (z == 1) ? wk : wv;
  int m0 = blockIdx.x * 128, n0 = blockIdx.y * 128;
  f32x4 acc[4][4];
#pragma unroll
  for (int i = 0; i < 4; i++)
#pragma unroll
    for (int j = 0; j < 4; j++) acc[i][j] = (f32x4){0.f, 0.f, 0.f, 0.f};

  int tid = threadIdx.x, wave = tid >> 6, lane = tid & 63;
  int lane15 = lane & 15, quad = lane >> 4;
  const float kQs = 0.022097086912079608f * 1.4426950408889634f;  // 1/sqrt(2048)*log2(e)

  if (z < 2) {
    gemm_main<true>(xb, W, As, Bs, m0, n0, K, acc);
    u16* Out = z ? Kb : Qb;
    float sc = z ? 1.0f : kQs;
    __syncthreads();  // mainloop LDS reads done everywhere
    // swapped: feat f = wn+ni*16+quad*4+r, token t = wm+mi*16+lane15
    // LDS [t][f]: 8B units u=f>>2 (0..31), phys u' = u ^ (t&31)
    {
      int wm = (wave >> 1) * 64, wn4 = (wave & 1) * 16;
      int t0 = wm + lane15;
#pragma unroll
      for (int mi = 0; mi < 4; mi++) {
        int t = t0 + mi * 16;
#pragma unroll
        for (int ni = 0; ni < 4; ni++) {
          int u = wn4 + ni * 4 + quad;
          u32 lo = pack_rne(acc[mi][ni][0] * sc, acc[mi][ni][1] * sc);
          u32 hi = pack_rne(acc[mi][ni][2] * sc, acc[mi][ni][3] * sc);
          *(uint2*)&SH[t * 128 + (u ^ (t & 31)) * 4] = (uint2){lo, hi};
        }
      }
    }
    __syncthreads();
    {
      int t = tid >> 1, half = tid & 1;
      size_t gbase = (size_t)(m0 + t) * 1024 + n0 + half * 64;
#pragma unroll
      for (int j = 0; j < 16; j += 2) {
        uint2 a = *(const uint2*)&SH[t * 128 + (((half * 16 + j) ^ (t & 31)) * 4)];
        uint2 b = *(const uint2*)&SH[t * 128 + (((half * 16 + j + 1) ^ (t & 31)) * 4)];
        uint4 o = (uint4){a.x, a.y, b.x, b.y};
        *(uint4*)&Out[gbase + j * 4] = o;
      }
    }
  } else {
    gemm_main<false>(xb, W, As, Bs, m0, n0, K, acc);
    __syncthreads();
    // classic: token tl = wm+mi*16+quad*4+r, feat fl = wn+ni*16+lane15
    // LDS [f][t]: 8B units u=tl>>2 (0..31), phys u' = u ^ (f&31)
    {
      int wm4 = (wave >> 1) * 16, wn = (wave & 1) * 64;
      int f0 = wn + lane15;
#pragma unroll
      for (int ni = 0; ni < 4; ni++) {
        int f = f0 + ni * 16;
#pragma unroll
        for (int mi = 0; mi < 4; mi++) {
          int u = wm4 + mi * 4 + quad;
          u32 lo = pack_rne(acc[mi][ni][0], acc[mi][ni][1]);
          u32 hi = pack_rne(acc[mi][ni][2], acc[mi][ni][3]);
          *(uint2*)&SH[f * 128 + (u ^ (f & 31)) * 4] = (uint2){lo, hi};
        }
      }
    }
    __syncthreads();
    {
      int f = tid >> 1, half = tid & 1;
      int bb = m0 >> 11, nn = (m0 & 2047) + half * 64;
      size_t gbase = (size_t)(bb * 1024 + n0 + f) * 2048 + nn;
#pragma unroll
      for (int j = 0; j < 16; j += 2) {
        uint2 a = *(const uint2*)&SH[f * 128 + (((half * 16 + j) ^ (f & 31)) * 4)];
        uint2 b = *(const uint2*)&SH[f * 128 + (((half * 16 + j + 1) ^ (f & 31)) * 4)];
        uint4 o = (uint4){a.x, a.y, b.x, b.y};
        *(uint4*)&Vtg[gbase + j * 4] = o;
      }
    }
  }
}

// Output projection, 128M x 64N tiles, swapped mainloop + LDS-transposed fp32 epilogue.
__global__ __launch_bounds__(256, 2) void gemm_out(const u16* __restrict__ A, const u16* __restrict__ W,
                                                   float* __restrict__ Of, const float* __restrict__ bias) {
  __shared__ __align__(16) u16 SH[16384];  // mainloop: As(8K)|Bs(4K) u16; epilogue: 128x64 f32
  u16* As = SH;
  u16* Bs = SH + 8192;
  const int K = 1024;
  int m0 = blockIdx.x * 128, n0 = blockIdx.y * 64;
  int tid = threadIdx.x, wave = tid >> 6, lane = tid & 63;
  int lane15 = lane & 15, quad = lane >> 4;
  int wm = (wave >> 1) * 64, wn = (wave & 1) * 32;
  f32x4 acc[4][2];
#pragma unroll
  for (int i = 0; i < 4; i++)
#pragma unroll
    for (int j = 0; j < 2; j++) acc[i][j] = (f32x4){0.f, 0.f, 0.f, 0.f};
  for (int k0 = 0; k0 < K; k0 += 64) {
    __syncthreads();
#pragma unroll
    for (int i = 0; i < 4; i++) {
      int rbase = wave * 32 + i * 8;
      int rloc = rbase + (lane >> 3);
      int ca = ((lane & 7) ^ (rloc & 7)) * 8;
      GLOAD_LDS16(A + (size_t)(m0 + rloc) * K + k0 + ca, As + rbase * 64);
    }
#pragma unroll
    for (int i = 0; i < 2; i++) {
      int rbase = wave * 16 + i * 8;
      int rloc = rbase + (lane >> 3);
      int ca = ((lane & 7) ^ (rloc & 7)) * 8;
      GLOAD_LDS16(W + (size_t)(n0 + rloc) * K + k0 + ca, Bs + rbase * 64);
    }
    __syncthreads();
#pragma unroll
    for (int kc = 0; kc < 2; kc++) {
      bf16x8 a[4], b[2];
#pragma unroll
      for (int mi = 0; mi < 4; mi++) {
        int m = wm + mi * 16 + lane15;
        a[mi] = *(const bf16x8*)(As + m * 64 + (((kc * 4 + quad) ^ (m & 7)) * 8));
      }
#pragma unroll
      for (int ni = 0; ni < 2; ni++) {
        int n = wn + ni * 16 + lane15;
        b[ni] = *(const bf16x8*)(Bs + n * 64 + (((kc * 4 + quad) ^ (n & 7)) * 8));
      }
#pragma unroll
      for (int mi = 0; mi < 4; mi++)
#pragma unroll
        for (int ni = 0; ni < 2; ni++)
          acc[mi][ni] = __builtin_amdgcn_mfma_f32_16x16x32_bf16(b[ni], a[mi], acc[mi][ni], 0, 0, 0);
    }
  }
  // swapped: feat f = wn+ni*16+quad*4+r (0..63), token t = wm+mi*16+lane15 (0..127)
  // LDS f32 [t][f]: 16B units u=f>>2 (0..15), phys u' = u ^ (t&15)
  float* F = (float*)SH;
  __syncthreads();
  {
    int wn8 = (wave & 1) * 8;
    int t0 = wm + lane15;
#pragma unroll
    for (int mi = 0; mi < 4; mi++) {
      int t = t0 + mi * 16;
#pragma unroll
      for (int ni = 0; ni < 2; ni++) {
        int u = wn8 + ni * 4 + quad;
        *(f32x4*)&F[t * 64 + (u ^ (t & 15)) * 4] = acc[mi][ni];
      }
    }
  }
  __syncthreads();
  {
    int t = tid >> 1, half = tid & 1;
    size_t gbase = (size_t)(m0 + t) * 1024 + n0;
#pragma unroll
    for (int j = 0; j < 8; j++) {
      int uu = half * 8 + j;
      f32x4 v = *(const f32x4*)&F[t * 64 + ((uu ^ (t & 15)) * 4)];
      float4 bb = *(const float4*)&bias[n0 + uu * 4];
      float4 o;
      o.x = v[0] + bb.x; o.y = v[1] + bb.y; o.z = v[2] + bb.z; o.w = v[3] + bb.w;
      *(float4*)&Of[gbase + uu * 4] = o;
    }
  }
}

// ---------------- flash attention v7: register P-exchange, 4 blocks/CU (unchanged) ----------------
__global__ __launch_bounds__(256, 4) void attn7(const u16* __restrict__ Q, const u16* __restrict__ Kg,
                                                const u16* __restrict__ Vtg, u16* __restrict__ ctx) {
  __shared__ __align__(16) u16 SH[16384];
  int tid = threadIdx.x, wave = tid >> 6, lane = tid & 63;
  int l31 = lane & 31, hf = lane >> 5;
  int qt = wave & 1, kvh = wave >> 1;

  int bh = blockIdx.x, by = blockIdx.y;
  int sidx = (by < 16) ? (31 - by) : (by - 16);
  int b = bh >> 4, h = bh & 15;
  int qbase = sidx * 64;

  bf16x8 qb[4];
#pragma unroll
  for (int s = 0; s < 4; s++)
    qb[s] = *(const bf16x8*)&Q[(size_t)(b * 2048 + qbase + qt * 32 + l31) * 1024 +
                               h * 64 + s * 16 + hf * 8];

  f32x16 oacc[2];
#pragma unroll
  for (int dt = 0; dt < 2; dt++)
#pragma unroll
    for (int r = 0; r < 16; r++) oacc[dt][r] = 0.f;
  float lsum = 0.f;

  auto stage = [&](int t, int d) {
    int tb = t * 64;
    u16* Kd = SH + d * 4096;
    u16* Vd = SH + 8192 + d * 4096;
#pragma unroll
    for (int i = 0; i < 2; i++) {
      int rbase = wave * 16 + i * 8;
      int rk = rbase + (lane >> 3);
      int ca = ((lane & 7) ^ (rk & 7)) * 8;
      GLOAD_LDS16(&Kg[(size_t)(b * 2048 + tb + rk) * 1024 + h * 64 + ca], Kd + rbase * 64);
      GLOAD_LDS16(&Vtg[(size_t)(b * 1024 + h * 64 + rk) * 2048 + tb + ca], Vd + rbase * 64);
    }
  };

  stage(0, 0);
  for (int t = 0; t <= sidx; ++t) {
    __syncthreads();
    if (t < sidx) stage(t + 1, (t + 1) & 1);
    int d = t & 1;
    const u16* Kd = SH + d * 4096;
    const u16* Vd = SH + 8192 + d * 4096;

    bool diag = (t == sidx);
    if (diag && kvh > qt) continue;

    int krow = kvh * 32 + l31;
    const u16* kp = Kd + krow * 64;
    bf16x8 kf[4];
#pragma unroll
    for (int s = 0; s < 4; s++)
      kf[s] = *(const bf16x8*)(kp + (((2 * s + hf) ^ (krow & 7)) * 8));

    f32x16 sv;
#pragma unroll
    for (int r = 0; r < 16; r++) sv[r] = 0.f;
#pragma unroll
    for (int s = 0; s < 4; s++)
      sv = __builtin_amdgcn_mfma_f32_32x32x16_bf16(kf[s], qb[s], sv, 0, 0, 0);

    if (diag && kvh == qt) {
#pragma unroll
      for (int r = 0; r < 16; r++) {
        int kvloc = (r & 3) + 8 * (r >> 2) + 4 * hf;
        if (kvloc > l31) sv[r] = -10000.0f;
      }
    }
#pragma unroll
    for (int r = 0; r < 16; r++) {
      float p = __builtin_amdgcn_exp2f(sv[r]);
      sv[r] = p; lsum += p;
    }
    u32 p0 = pack_bf2(sv[0], sv[1]),   p1 = pack_bf2(sv[2], sv[3]);
    u32 p2 = pack_bf2(sv[4], sv[5]),   p3 = pack_bf2(sv[6], sv[7]);
    u32 p4 = pack_bf2(sv[8], sv[9]),   p5 = pack_bf2(sv[10], sv[11]);
    u32 p6 = pack_bf2(sv[12], sv[13]), p7 = pack_bf2(sv[14], sv[15]);
    u32 x0 = __shfl_xor(hf ? p0 : p2, 32);
    u32 x1 = __shfl_xor(hf ? p1 : p3, 32);
    u32 x2 = __shfl_xor(hf ? p4 : p6, 32);
    u32 x3 = __shfl_xor(hf ? p5 : p7, 32);
    union U8 { u32 u[4]; bf16x8 v; };
    U8 pf0, pf1;
    pf0.u[0] = hf ? x0 : p0; pf0.u[1] = hf ? x1 : p1;
    pf0.u[2] = hf ? p2 : x0; pf0.u[3] = hf ? p3 : x1;
    pf1.u[0] = hf ? x2 : p4; pf1.u[1] = hf ? x3 : p5;
    pf1.u[2] = hf ? p6 : x2; pf1.u[3] = hf ? p7 : x3;

#pragma unroll
    for (int c = 0; c < 2; c++) {
      bf16x8 pf = c ? pf1.v : pf0.v;
#pragma unroll
      for (int dt = 0; dt < 2; dt++) {
        int vrow = dt * 32 + l31;
        bf16x8 va = *(const bf16x8*)(Vd + vrow * 64 + (((4 * kvh + 2 * c + hf) ^ (vrow & 7)) * 8));
        oacc[dt] = __builtin_amdgcn_mfma_f32_32x32x16_bf16(va, pf, oacc[dt], 0, 0, 0);
      }
    }
  }

  lsum += __shfl_xor(lsum, 32);
  float* MG = (float*)SH;
  float* LS = (float*)(SH + 8192);
  __syncthreads();
  if (kvh == 1) {
#pragma unroll
    for (int dt = 0; dt < 2; dt++) {
      float* p = MG + ((qt * 2 + dt) * 64 + lane) * 16;
#pragma unroll
      for (int gr = 0; gr < 4; gr++)
        *(f32x4*)(p + gr * 4) = (f32x4){oacc[dt][4 * gr], oacc[dt][4 * gr + 1],
                                        oacc[dt][4 * gr + 2], oacc[dt][4 * gr + 3]};
    }
    LS[qt * 32 + l31] = lsum;
  }
  __syncthreads();
  if (kvh == 0) {
    float inv = 1.0f / (lsum + LS[qt * 32 + l31]);
    int token = qbase + qt * 32 + l31;
    size_t off = (size_t)(b * 2048 + token) * 1024 + h * 64;
#pragma unroll
    for (int dt = 0; dt < 2; dt++) {
      const float* p = MG + ((qt * 2 + dt) * 64 + lane) * 16;
#pragma unroll
      for (int gr = 0; gr < 4; gr++) {
        f32x4 m = *(const f32x4*)(p + gr * 4);
        ushort4 o;
        o.x = f2bf((oacc[dt][4 * gr + 0] + m[0]) * inv);
        o.y = f2bf((oacc[dt][4 * gr + 1] + m[1]) * inv);
        o.z = f2bf((oacc[dt][4 * gr + 2] + m[2]) * inv);
        o.w = f2bf((oacc[dt][4 * gr + 3] + m[3]) * inv);
        *(ushort4*)&ctx[off + dt * 32 + 8 * gr + 4 * hf] = o;
      }
    }
  }
}

extern "C" void kernel_launch(void* const* d_in, const int* in_sizes, int n_in,
                              void* d_out, int out_size, void* d_ws, size_t ws_size,
                              hipStream_t stream) {
  const float* x  = (const float*)d_in[0];
  const float* Wq = (const float*)d_in[1];
  const float* Wk = (const float*)d_in[2];
  const float* Wv = (const float*)d_in[3];
  const float* Wo = (const float*)d_in[4];
  const float* bo = (const float*)d_in[5];
  float* out = (float*)d_out;
  char* ws = (char*)d_ws;
  const size_t MB = 1024 * 1024;
  u16* xb   = (u16*)(ws);
  u16* wqb  = (u16*)(ws +  8 * MB);
  u16* wkb  = (u16*)(ws + 10 * MB);
  u16* wvb  = (u16*)(ws + 12 * MB);
  u16* wob  = (u16*)(ws + 14 * MB);
  u16* Qb   = (u16*)(ws + 16 * MB);
  u16* Kb   = (u16*)(ws + 24 * MB);
  u16* Vtg  = (u16*)(ws + 32 * MB);  // V^T: [b,h,dh,n]
  u16* ctxb = (u16*)(ws + 40 * MB);

  conv_all<<<dim3(1024, 8), 256, 0, stream>>>(x, Wq, Wk, Wv, Wo, xb, wqb, wkb, wvb, wob);
  gemm_qkv<<<dim3(32, 8, 3), 256, 0, stream>>>(xb, wqb, wkb, wvb, Qb, Kb, Vtg);
  attn7<<<dim3(32, 32), 256, 0, stream>>>(Qb, Kb, Vtg, ctxb);
  gemm_out<<<dim3(32, 16), 256, 0, stream>>>(ctxb, wob, out, bo);
}